// Round 1
// baseline (513.205 us; speedup 1.0000x reference)
//
#include <hip/hip_runtime.h>
#include <hip/hip_bf16.h>

// ---------------- problem constants ----------------
#define HD    1152
#define NHD   16        // heads
#define DH    72        // head dim
#define DHP   96        // padded head dim (3 x 32 for mfma K)
#define NB    16        // batch
#define SEQ   729
#define SP    736       // seq padded to x32 for K tiles
#define MTOT  (NB*SEQ)  // 11664
#define MPAD  11776     // 92 * 128
#define VROWS 80        // V dim rows padded to 5 x 16
#define ATT_SCALE 0.117851130197757930f  // 72^-0.5

typedef __attribute__((ext_vector_type(8))) short short8;
typedef __attribute__((ext_vector_type(4))) float f32x4;

__device__ __forceinline__ unsigned short f2bf(float x){
  unsigned u = __float_as_uint(x);
  u += 0x7FFFu + ((u >> 16) & 1u);   // RNE
  return (unsigned short)(u >> 16);
}

#define GLD16(g, s) __builtin_amdgcn_global_load_lds( \
    (const __attribute__((address_space(1))) void*)(g), \
    (__attribute__((address_space(3))) void*)(s), 16, 0, 0)

// ---------------- workspace layout (bytes) ----------------
// hsb (also reused as ctx after QKV GEMM consumed it)
#define OFF_HSB   ((size_t)0)                       // MPAD*HD*2      = 27131904
#define OFF_WQKV  ((size_t)27131904)                // 3456*HD*2      =  7962624
#define OFF_WO    ((size_t)(27131904+7962624))      // HD*HD*2        =  2654208
#define OFF_Q     ((size_t)37748736)                // 256*SEQ*DHP*2  = 35831808
#define OFF_K     ((size_t)(37748736+35831808))     // 256*SP*DHP*2   = 36175872
#define OFF_V     ((size_t)(37748736+35831808+36175872)) // 256*VROWS*SP*2 = 30146560
#define WS_END    ((size_t)(37748736+35831808+36175872+30146560))
#define ZERO_BYTES ((size_t)(35831808+36175872+30146560))

// ---------------- fp32 -> bf16 convert (hidden states) ----------------
__global__ void cvt_hs_kernel(const float* __restrict__ in,
                              unsigned short* __restrict__ out, int n4){
  int i = blockIdx.x*256 + threadIdx.x;
  if (i >= n4) return;
  float4 v = ((const float4*)in)[i];
  ushort4 o;
  o.x = f2bf(v.x); o.y = f2bf(v.y); o.z = f2bf(v.z); o.w = f2bf(v.w);
  ((ushort4*)out)[i] = o;
}

// ---------------- weight transpose + convert: out[n][k] = bf16(W[k][n]) ----------------
__global__ void wt_cvt_kernel(const float* __restrict__ W,
                              unsigned short* __restrict__ outT){
  __shared__ float t[32][33];
  int k0 = blockIdx.x*32, n0 = blockIdx.y*32;
  int tx = threadIdx.x, ty = threadIdx.y;   // (32, 8)
  #pragma unroll
  for (int j=0;j<32;j+=8) t[ty+j][tx] = W[(size_t)(k0+ty+j)*HD + n0 + tx];
  __syncthreads();
  #pragma unroll
  for (int j=0;j<32;j+=8) outT[(size_t)(n0+ty+j)*HD + k0 + tx] = f2bf(t[tx][ty+j]);
}

// ---------------- bf16 GEMM: C[M][N] = A[M][K] * BT[N][K]^T ----------------
// MODE 0: O-proj -> fp32 out + bias  (TILES_N = 9)
// MODE 1: QKV    -> scatter to padded Q/K/Vt + bias (TILES_N = 27)
template<int MODE>
__global__ __launch_bounds__(256) void gemm_kernel(
    const unsigned short* __restrict__ A, const unsigned short* __restrict__ BT,
    const float* __restrict__ bias_q, const float* __restrict__ bias_k,
    const float* __restrict__ bias_v,
    float* __restrict__ outF,
    unsigned short* __restrict__ Qp, unsigned short* __restrict__ Kp,
    unsigned short* __restrict__ Vt)
{
  constexpr int TILES_N = (MODE==1) ? 27 : 9;
  const int tn = blockIdx.x % TILES_N, tm = blockIdx.x / TILES_N;
  const int tid = threadIdx.x, w = tid>>6, l = tid&63;
  const int lr = l&15, lg = l>>4;
  const int wm = w>>1, wn = w&1;

  __shared__ __align__(16) unsigned short As[128*32];
  __shared__ __align__(16) unsigned short Bs[128*32];

  const f32x4 z4 = {0.f,0.f,0.f,0.f};
  f32x4 acc[4][4];
  #pragma unroll
  for (int i=0;i<4;i++)
    #pragma unroll
    for (int j=0;j<4;j++) acc[i][j] = z4;

  // staging: wave w loads rows [w*32, w*32+32) of each 128x32 tile; lane -> row l>>2, col (l&3)*8
  const unsigned short* gA = A  + (size_t)(tm*128 + w*32 + (l>>2))*HD + (l&3)*8;
  const unsigned short* gB = BT + (size_t)(tn*128 + w*32 + (l>>2))*HD + (l&3)*8;
  unsigned short* lA = As + w*1024;
  unsigned short* lB = Bs + w*1024;

  for (int kb=0; kb<HD; kb+=32){
    GLD16(gA + kb,          lA);
    GLD16(gA + kb + 16*HD,  lA + 512);
    GLD16(gB + kb,          lB);
    GLD16(gB + kb + 16*HD,  lB + 512);
    __syncthreads();
    short8 af[4], bf[4];
    #pragma unroll
    for (int mi=0;mi<4;mi++) af[mi] = *(const short8*)(As + (wm*64 + mi*16 + lr)*32 + lg*8);
    #pragma unroll
    for (int ni=0;ni<4;ni++) bf[ni] = *(const short8*)(Bs + (wn*64 + ni*16 + lr)*32 + lg*8);
    #pragma unroll
    for (int mi=0;mi<4;mi++)
      #pragma unroll
      for (int ni=0;ni<4;ni++)
        acc[mi][ni] = __builtin_amdgcn_mfma_f32_16x16x32_bf16(af[mi], bf[ni], acc[mi][ni], 0, 0, 0);
    __syncthreads();
  }

  if (MODE == 0){
    #pragma unroll
    for (int mi=0;mi<4;mi++){
      #pragma unroll
      for (int j=0;j<4;j++){
        int m = tm*128 + wm*64 + mi*16 + lg*4 + j;
        if (m < MTOT){
          #pragma unroll
          for (int ni=0;ni<4;ni++){
            int n = tn*128 + wn*64 + ni*16 + lr;
            outF[(size_t)m*HD + n] = acc[mi][ni][j] + bias_q[n];
          }
        }
      }
    }
  } else {
    #pragma unroll
    for (int mi=0;mi<4;mi++){
      #pragma unroll
      for (int j=0;j<4;j++){
        int m = tm*128 + wm*64 + mi*16 + lg*4 + j;
        if (m >= MTOT) continue;
        int b = m / SEQ;
        int s = m - b*SEQ;
        #pragma unroll
        for (int ni=0;ni<4;ni++){
          int n = tn*128 + wn*64 + ni*16 + lr;
          int mat = n / HD;
          int c = n - mat*HD;
          int h = c / DH;
          int d = c - h*DH;
          const float* bias = (mat==0) ? bias_q : (mat==1) ? bias_k : bias_v;
          float v = acc[mi][ni][j] + bias[c];
          unsigned short bv16 = f2bf(v);
          int bh = b*NHD + h;
          if (mat == 0)      Qp[(size_t)bh*(SEQ*DHP) + (size_t)s*DHP + d] = bv16;
          else if (mat == 1) Kp[(size_t)bh*(SP*DHP)  + (size_t)s*DHP + d] = bv16;
          else               Vt[(size_t)bh*(VROWS*SP) + (size_t)d*SP + s] = bv16;
        }
      }
    }
  }
}

// ---------------- fused attention (per (b,h), 64 q-rows per block, 4 waves) ----------------
__global__ __launch_bounds__(256) void attn_kernel(
    const unsigned short* __restrict__ Qp, const unsigned short* __restrict__ Kp,
    const unsigned short* __restrict__ Vt, unsigned short* __restrict__ ctx)
{
  const int qt = blockIdx.x;       // 0..11
  const int bh = blockIdx.y;       // 0..255
  const int tid = threadIdx.x, w = tid>>6, l = tid&63;
  const int lr = l&15, lg = l>>4;

  const unsigned short* Qb = Qp + (size_t)bh*(SEQ*DHP);
  const unsigned short* Kb = Kp + (size_t)bh*(SP*DHP);
  const unsigned short* Vb = Vt + (size_t)bh*(VROWS*SP);

  __shared__ __align__(16) unsigned short Plds[4][16][40];  // per-wave P tile, stride 40 (bank-friendly)

  const int qlocal = qt*64 + w*16;           // first q-row of this wave
  int qr = qlocal + lr; if (qr > SEQ-1) qr = SEQ-1;   // clamp (stores masked later)

  short8 qf[3];
  #pragma unroll
  for (int kk=0;kk<3;kk++) qf[kk] = *(const short8*)(Qb + (size_t)qr*DHP + kk*32 + lg*8);

  const f32x4 z4 = {0.f,0.f,0.f,0.f};
  f32x4 o[5];
  #pragma unroll
  for (int i=0;i<5;i++) o[i] = z4;
  float mrun[4] = {-1e30f,-1e30f,-1e30f,-1e30f};
  float lrun[4] = {0.f,0.f,0.f,0.f};

  for (int kt=0; kt<23; kt++){
    const int kb = kt*32;
    f32x4 s0 = z4, s1 = z4;
    const int c0 = kb + lr, c1 = kb + 16 + lr;
    #pragma unroll
    for (int kk=0;kk<3;kk++){
      short8 kf0 = *(const short8*)(Kb + (size_t)c0*DHP + kk*32 + lg*8);
      s0 = __builtin_amdgcn_mfma_f32_16x16x32_bf16(qf[kk], kf0, s0, 0, 0, 0);
    }
    #pragma unroll
    for (int kk=0;kk<3;kk++){
      short8 kf1 = *(const short8*)(Kb + (size_t)c1*DHP + kk*32 + lg*8);
      s1 = __builtin_amdgcn_mfma_f32_16x16x32_bf16(qf[kk], kf1, s1, 0, 0, 0);
    }
    const bool ok0 = (c0 < SEQ), ok1 = (c1 < SEQ);
    float p0[4], p1[4], sc[4];
    #pragma unroll
    for (int j=0;j<4;j++){
      float a = ok0 ? s0[j]*ATT_SCALE : -1e30f;
      float b = ok1 ? s1[j]*ATT_SCALE : -1e30f;
      float t = fmaxf(a, b);
      #pragma unroll
      for (int off=1; off<16; off<<=1) t = fmaxf(t, __shfl_xor(t, off));
      float mn = fmaxf(mrun[j], t);
      float so = __expf(mrun[j] - mn);
      mrun[j] = mn; sc[j] = so;
      float e0 = ok0 ? __expf(a - mn) : 0.f;
      float e1 = ok1 ? __expf(b - mn) : 0.f;
      p0[j] = e0; p1[j] = e1;
      float su = e0 + e1;
      #pragma unroll
      for (int off=1; off<16; off<<=1) su += __shfl_xor(su, off);
      lrun[j] = lrun[j]*so + su;
    }
    #pragma unroll
    for (int i=0;i<5;i++){
      f32x4 t = o[i];
      #pragma unroll
      for (int j=0;j<4;j++) t[j] *= sc[j];
      o[i] = t;
    }
    // P -> LDS (wave-private; same-wave LDS ops are ordered)
    #pragma unroll
    for (int j=0;j<4;j++){
      Plds[w][lg*4+j][lr]      = f2bf(p0[j]);
      Plds[w][lg*4+j][16 + lr] = f2bf(p1[j]);
    }
    short8 pf = *(const short8*)(&Plds[w][lr][lg*8]);
    #pragma unroll
    for (int i=0;i<5;i++){
      short8 vf = *(const short8*)(Vb + (size_t)(i*16 + lr)*SP + kb + lg*8);
      o[i] = __builtin_amdgcn_mfma_f32_16x16x32_bf16(pf, vf, o[i], 0, 0, 0);
    }
  }

  const int b = bh >> 4, h = bh & 15;
  #pragma unroll
  for (int j=0;j<4;j++){
    int m = qlocal + lg*4 + j;
    if (m >= SEQ) continue;
    float inv = 1.f / lrun[j];
    #pragma unroll
    for (int i=0;i<5;i++){
      int d = i*16 + lr;
      if (d < DH)
        ctx[((size_t)(b*SEQ + m))*HD + h*DH + d] = f2bf(o[i][j]*inv);
    }
  }
}

// ---------------- launcher ----------------
extern "C" void kernel_launch(void* const* d_in, const int* in_sizes, int n_in,
                              void* d_out, int out_size, void* d_ws, size_t ws_size,
                              hipStream_t stream) {
  const float* hs = (const float*)d_in[0];
  const float* Wq = (const float*)d_in[1]; const float* bq = (const float*)d_in[2];
  const float* Wk = (const float*)d_in[3]; const float* bk = (const float*)d_in[4];
  const float* Wv = (const float*)d_in[5]; const float* bv = (const float*)d_in[6];
  const float* Wo = (const float*)d_in[7]; const float* bo = (const float*)d_in[8];
  float* out = (float*)d_out;
  char* ws = (char*)d_ws;
  if (ws_size < WS_END) return;

  unsigned short* hsb   = (unsigned short*)(ws + OFF_HSB);  // later reused as ctx
  unsigned short* wqkvT = (unsigned short*)(ws + OFF_WQKV);
  unsigned short* woT   = (unsigned short*)(ws + OFF_WO);
  unsigned short* Qp    = (unsigned short*)(ws + OFF_Q);
  unsigned short* Kp    = (unsigned short*)(ws + OFF_K);
  unsigned short* Vt    = (unsigned short*)(ws + OFF_V);
  unsigned short* ctx   = hsb;

  // 1. convert hidden states to bf16
  int n4 = MTOT*HD/4;
  cvt_hs_kernel<<<(n4+255)/256, 256, 0, stream>>>(hs, hsb, n4);

  // 2. weights: transpose + convert to bf16 (n-major)
  dim3 bt(32, 8), gt(HD/32, HD/32);
  wt_cvt_kernel<<<gt, bt, 0, stream>>>(Wq, wqkvT);
  wt_cvt_kernel<<<gt, bt, 0, stream>>>(Wk, wqkvT + (size_t)HD*HD);
  wt_cvt_kernel<<<gt, bt, 0, stream>>>(Wv, wqkvT + (size_t)2*HD*HD);
  wt_cvt_kernel<<<gt, bt, 0, stream>>>(Wo, woT);

  // 3. zero padded Q/K/Vt (pads must be exact zeros for MFMA spans / masked cols)
  hipMemsetAsync(ws + OFF_Q, 0, ZERO_BYTES, stream);

  // 4. QKV projection GEMM (M=11776pad, N=3456, K=1152), scatter epilogue
  gemm_kernel<1><<<(MPAD/128)*27, 256, 0, stream>>>(hsb, wqkvT, bq, bk, bv,
                                                    nullptr, Qp, Kp, Vt);

  // 5. fused attention -> ctx [MTOT][1152] bf16 (reuses hsb buffer)
  attn_kernel<<<dim3(12, 256), 256, 0, stream>>>(Qp, Kp, Vt, ctx);

  // 6. output projection GEMM -> fp32 out + bo
  gemm_kernel<0><<<(MPAD/128)*9, 256, 0, stream>>>(ctx, woT, bo, nullptr, nullptr,
                                                   out, nullptr, nullptr, nullptr);
}

// Round 2
// 430.482 us; speedup vs baseline: 1.1922x; 1.1922x over previous
//
#include <hip/hip_runtime.h>
#include <hip/hip_bf16.h>

// ---------------- problem constants ----------------
#define HD    1152
#define NHD   16        // heads
#define DH    72        // head dim
#define DHP   80        // padded head dim (5 x 16 for mfma K-chunks)
#define NB    16        // batch
#define SEQ   729
#define SP    736       // seq padded to x32 for K tiles
#define MTOT  (NB*SEQ)  // 11664
#define MPAD  11776     // 92 * 128
#define VROWS 96        // V d-rows padded to 3 x 32
// fold head_dim^-0.5 * log2(e) into Q so softmax runs in exp2 domain
#define QSCALE (0.117851130197757930f * 1.4426950408889634f)

typedef __attribute__((ext_vector_type(8))) short short8;
typedef __attribute__((ext_vector_type(4))) float f32x4;
typedef __attribute__((ext_vector_type(16))) float f32x16;
typedef __attribute__((ext_vector_type(4))) unsigned u32x4;

__device__ __forceinline__ unsigned short f2bf(float x){
  unsigned u = __float_as_uint(x);
  u += 0x7FFFu + ((u >> 16) & 1u);   // RNE
  return (unsigned short)(u >> 16);
}

__device__ __forceinline__ unsigned cvtpk_bf16(float lo, float hi){
  unsigned r;
  asm("v_cvt_pk_bf16_f32 %0, %1, %2" : "=v"(r) : "v"(lo), "v"(hi));
  return r;
}

#define GLD16(g, s) __builtin_amdgcn_global_load_lds( \
    (const __attribute__((address_space(1))) void*)(g), \
    (__attribute__((address_space(3))) void*)(s), 16, 0, 0)

// ---------------- workspace layout (bytes) ----------------
#define OFF_HSB   ((size_t)0)                    // MPAD*HD*2        = 27131904
#define OFF_WQKV  ((size_t)27131904)             // 3456*HD*2        =  7962624
#define OFF_WO    ((size_t)35094528)             // HD*HD*2          =  2654208
#define OFF_Q     ((size_t)37748736)             // 256*SEQ*DHP*2    = 29859840
#define OFF_K     ((size_t)67608576)             // 256*SP*DHP*2     = 30146560
#define OFF_V     ((size_t)97755136)             // 256*VROWS*SP*2   = 36175872
#define WS_END    ((size_t)133931008)
#define Q_BYTES   ((size_t)29859840)

// ---------------- fp32 -> bf16 convert (hidden states) ----------------
__global__ void cvt_hs_kernel(const float* __restrict__ in,
                              unsigned short* __restrict__ out, int n4){
  int i = blockIdx.x*256 + threadIdx.x;
  if (i >= n4) return;
  float4 v = ((const float4*)in)[i];
  ushort4 o;
  o.x = f2bf(v.x); o.y = f2bf(v.y); o.z = f2bf(v.z); o.w = f2bf(v.w);
  ((ushort4*)out)[i] = o;
}

// ---------------- weight transpose + convert: out[n][k] = bf16(W[k][n]) ----------------
__global__ void wt_cvt_kernel(const float* __restrict__ W,
                              unsigned short* __restrict__ outT){
  __shared__ float t[32][33];
  int k0 = blockIdx.x*32, n0 = blockIdx.y*32;
  int tx = threadIdx.x, ty = threadIdx.y;   // (32, 8)
  #pragma unroll
  for (int j=0;j<32;j+=8) t[ty+j][tx] = W[(size_t)(k0+ty+j)*HD + n0 + tx];
  __syncthreads();
  #pragma unroll
  for (int j=0;j<32;j+=8) outT[(size_t)(n0+ty+j)*HD + k0 + tx] = f2bf(t[tx][ty+j]);
}

// ---------------- bf16 GEMM: C[M][N] = A[M][K] * BT[N][K]^T ----------------
// MODE 0: O-proj -> fp32 out + bias  (TILES_N = 9)
// MODE 1: QKV    -> scatter to padded Q/K/Vt + bias (TILES_N = 27)
template<int MODE>
__global__ __launch_bounds__(256) void gemm_kernel(
    const unsigned short* __restrict__ A, const unsigned short* __restrict__ BT,
    const float* __restrict__ bias_q, const float* __restrict__ bias_k,
    const float* __restrict__ bias_v,
    float* __restrict__ outF,
    unsigned short* __restrict__ Qp, unsigned short* __restrict__ Kp,
    unsigned short* __restrict__ Vt)
{
  constexpr int TILES_N = (MODE==1) ? 27 : 9;
  const int tn = blockIdx.x % TILES_N, tm = blockIdx.x / TILES_N;
  const int tid = threadIdx.x, w = tid>>6, l = tid&63;
  const int lr = l&15, lg = l>>4;
  const int wm = w>>1, wn = w&1;

  __shared__ __align__(16) unsigned short As[128*32];
  __shared__ __align__(16) unsigned short Bs[128*32];

  const f32x4 z4 = {0.f,0.f,0.f,0.f};
  f32x4 acc[4][4];
  #pragma unroll
  for (int i=0;i<4;i++)
    #pragma unroll
    for (int j=0;j<4;j++) acc[i][j] = z4;

  const unsigned short* gA = A  + (size_t)(tm*128 + w*32 + (l>>2))*HD + (l&3)*8;
  const unsigned short* gB = BT + (size_t)(tn*128 + w*32 + (l>>2))*HD + (l&3)*8;
  unsigned short* lA = As + w*1024;
  unsigned short* lB = Bs + w*1024;

  for (int kb=0; kb<HD; kb+=32){
    GLD16(gA + kb,          lA);
    GLD16(gA + kb + 16*HD,  lA + 512);
    GLD16(gB + kb,          lB);
    GLD16(gB + kb + 16*HD,  lB + 512);
    __syncthreads();
    short8 af[4], bf[4];
    #pragma unroll
    for (int mi=0;mi<4;mi++) af[mi] = *(const short8*)(As + (wm*64 + mi*16 + lr)*32 + lg*8);
    #pragma unroll
    for (int ni=0;ni<4;ni++) bf[ni] = *(const short8*)(Bs + (wn*64 + ni*16 + lr)*32 + lg*8);
    #pragma unroll
    for (int mi=0;mi<4;mi++)
      #pragma unroll
      for (int ni=0;ni<4;ni++)
        acc[mi][ni] = __builtin_amdgcn_mfma_f32_16x16x32_bf16(af[mi], bf[ni], acc[mi][ni], 0, 0, 0);
    __syncthreads();
  }

  if (MODE == 0){
    #pragma unroll
    for (int mi=0;mi<4;mi++){
      #pragma unroll
      for (int j=0;j<4;j++){
        int m = tm*128 + wm*64 + mi*16 + lg*4 + j;
        if (m < MTOT){
          #pragma unroll
          for (int ni=0;ni<4;ni++){
            int n = tn*128 + wn*64 + ni*16 + lr;
            outF[(size_t)m*HD + n] = acc[mi][ni][j] + bias_q[n];
          }
        }
      }
    }
  } else {
    #pragma unroll
    for (int mi=0;mi<4;mi++){
      #pragma unroll
      for (int j=0;j<4;j++){
        int m = tm*128 + wm*64 + mi*16 + lg*4 + j;
        if (m >= MTOT) continue;
        int b = m / SEQ;
        int s = m - b*SEQ;
        #pragma unroll
        for (int ni=0;ni<4;ni++){
          int n = tn*128 + wn*64 + ni*16 + lr;
          int mat = n / HD;
          int c = n - mat*HD;
          int h = c / DH;
          int d = c - h*DH;
          const float* bias = (mat==0) ? bias_q : (mat==1) ? bias_k : bias_v;
          float v = acc[mi][ni][j] + bias[c];
          int bh = b*NHD + h;
          if (mat == 0)      Qp[(size_t)bh*(SEQ*DHP) + (size_t)s*DHP + d] = f2bf(v*QSCALE);
          else if (mat == 1) Kp[(size_t)bh*(SP*DHP)  + (size_t)s*DHP + d] = f2bf(v);
          else               Vt[(size_t)bh*(VROWS*SP) + (size_t)d*SP + s] = f2bf(v);
        }
      }
    }
  }
}

// ---------------- PV sub-tile: pack P (in-register) -> bf16 frags, 6 MFMAs ----------------
__device__ __forceinline__ void pv_subtile(const f32x16 s, const unsigned short* __restrict__ vcol,
                                           int hi, f32x16 (&o)[3]){
  // s holds P[q][kcol_local] with kcol_local = (r&3)+8*(r>>2)+4*hi  (q = lane&31)
  unsigned A[4], B[4], xA[4], xB[4];
  #pragma unroll
  for (int g=0; g<4; g++){
    A[g]  = cvtpk_bf16(s[4*g+0], s[4*g+1]);
    B[g]  = cvtpk_bf16(s[4*g+2], s[4*g+3]);
    xA[g] = (unsigned)__shfl_xor((int)A[g], 32);
    xB[g] = (unsigned)__shfl_xor((int)B[g], 32);
  }
  #pragma unroll
  for (int ks=0; ks<2; ks++){
    // A-frag element j <-> kcol ks*16 + hi*8 + j
    unsigned w0 = hi ? xA[2*ks+1] : A[2*ks];
    unsigned w1 = hi ? xB[2*ks+1] : B[2*ks];
    unsigned w2 = hi ? A[2*ks+1]  : xA[2*ks];
    unsigned w3 = hi ? B[2*ks+1]  : xB[2*ks];
    u32x4 pw = {w0, w1, w2, w3};
    short8 pa = __builtin_bit_cast(short8, pw);
    #pragma unroll
    for (int dt=0; dt<3; dt++){
      short8 vf = *(const short8*)(vcol + (size_t)(dt*32)*SP + ks*16 + hi*8);
      o[dt] = __builtin_amdgcn_mfma_f32_32x32x16_bf16(pa, vf, o[dt], 0, 0, 0);
    }
  }
}

// ---------------- fused attention: 32 q-rows/wave, swapped QK^T, in-register softmax ----------------
__global__ __launch_bounds__(256) void attn_kernel(
    const unsigned short* __restrict__ Qp, const unsigned short* __restrict__ Kp,
    const unsigned short* __restrict__ Vt, unsigned short* __restrict__ ctx)
{
  const int blk = blockIdx.x;            // 0..1535
  const int xcd = blk & 7, ii = blk >> 3;
  const int bh  = xcd*32 + ii/6;         // 6 consecutive same-XCD blocks share one bh -> L2 reuse
  const int qt6 = ii % 6;
  const int tid = threadIdx.x, w = tid>>6, l = tid&63;
  const int lane = l & 31, hi = l >> 5;

  const int qbase = (qt6*4 + w)*32;
  if (qbase >= SEQ) return;              // wave-uniform; no barriers in this kernel

  const unsigned short* Qb = Qp + (size_t)bh*(SEQ*DHP);
  const unsigned short* Kb = Kp + (size_t)bh*(SP*DHP);
  const unsigned short* Vb = Vt + (size_t)bh*(VROWS*SP);

  int qr = qbase + lane; if (qr > SEQ-1) qr = SEQ-1;
  short8 qf[5];
  #pragma unroll
  for (int c=0;c<5;c++) qf[c] = *(const short8*)(Qb + (size_t)qr*DHP + c*16 + hi*8);

  f32x16 o[3];
  #pragma unroll
  for (int dt=0; dt<3; dt++)
    #pragma unroll
    for (int r=0;r<16;r++) o[dt][r] = 0.f;

  float m = -1e30f, lsum = 0.f;

  for (int kt=0; kt<12; kt++){
    const int kb = kt*64;
    f32x16 s0, s1;
    #pragma unroll
    for (int r=0;r<16;r++){ s0[r]=0.f; s1[r]=0.f; }

    const unsigned short* krow0 = Kb + (size_t)(kb + lane)*DHP + hi*8;
    #pragma unroll
    for (int c=0;c<5;c++){
      short8 kf = *(const short8*)(krow0 + c*16);
      s0 = __builtin_amdgcn_mfma_f32_32x32x16_bf16(kf, qf[c], s0, 0, 0, 0);
    }
    if (kt < 11){
      const unsigned short* krow1 = krow0 + 32*DHP;
      #pragma unroll
      for (int c=0;c<5;c++){
        short8 kf = *(const short8*)(krow1 + c*16);
        s1 = __builtin_amdgcn_mfma_f32_32x32x16_bf16(kf, qf[c], s1, 0, 0, 0);
      }
    } else {
      #pragma unroll
      for (int r=0;r<16;r++){
        const int base = 704 + (r&3) + 8*(r>>2);
        s0[r] = (base + 4*hi >= SEQ) ? -1e30f : s0[r];
        s1[r] = -1e30f;
      }
    }

    // per-lane = per-q row stats (S^T layout: col=lane&31=q)
    float tmax = -1e30f;
    #pragma unroll
    for (int r=0;r<16;r++) tmax = fmaxf(tmax, fmaxf(s0[r], s1[r]));
    tmax = fmaxf(tmax, __shfl_xor(tmax, 32));

    if (!__all(tmax <= m + 8.0f)){       // T13 defer-max (exp2 domain, THR=8)
      float mn = fmaxf(m, tmax);
      float sc = exp2f(m - mn);
      m = mn;
      lsum *= sc;
      #pragma unroll
      for (int dt=0; dt<3; dt++)
        #pragma unroll
        for (int r=0;r<16;r++) o[dt][r] *= sc;
    }

    float su = 0.f;
    #pragma unroll
    for (int r=0;r<16;r++){ float p = exp2f(s0[r]-m); s0[r]=p; su += p; }
    #pragma unroll
    for (int r=0;r<16;r++){ float p = exp2f(s1[r]-m); s1[r]=p; su += p; }
    su += __shfl_xor(su, 32);
    lsum += su;

    const unsigned short* vcol = Vb + (size_t)lane*SP + kb;
    pv_subtile(s0, vcol, hi, o);
    if (kt < 11) pv_subtile(s1, vcol + 32, hi, o);
  }

  // epilogue: O^ layout rows=q_local, cols=d; normalize by 1/lsum of the row's q
  float linv = 1.0f / lsum;
  const int b = bh >> 4, h = bh & 15;
  #pragma unroll
  for (int r=0;r<16;r++){
    const int qloc = (r&3) + 8*(r>>2) + 4*hi;
    float lv = __shfl(linv, qloc);
    int q = qbase + qloc;
    if (q < SEQ){
      unsigned short* crow = ctx + ((size_t)(b*SEQ + q))*HD + h*DH;
      #pragma unroll
      for (int dt=0; dt<3; dt++){
        int d = dt*32 + lane;
        if (d < DH) crow[d] = f2bf(o[dt][r] * lv);
      }
    }
  }
}

// ---------------- launcher ----------------
extern "C" void kernel_launch(void* const* d_in, const int* in_sizes, int n_in,
                              void* d_out, int out_size, void* d_ws, size_t ws_size,
                              hipStream_t stream) {
  const float* hs = (const float*)d_in[0];
  const float* Wq = (const float*)d_in[1]; const float* bq = (const float*)d_in[2];
  const float* Wk = (const float*)d_in[3]; const float* bk = (const float*)d_in[4];
  const float* Wv = (const float*)d_in[5]; const float* bv = (const float*)d_in[6];
  const float* Wo = (const float*)d_in[7]; const float* bo = (const float*)d_in[8];
  float* out = (float*)d_out;
  char* ws = (char*)d_ws;
  if (ws_size < WS_END) return;

  unsigned short* hsb   = (unsigned short*)(ws + OFF_HSB);  // later reused as ctx
  unsigned short* wqkvT = (unsigned short*)(ws + OFF_WQKV);
  unsigned short* woT   = (unsigned short*)(ws + OFF_WO);
  unsigned short* Qp    = (unsigned short*)(ws + OFF_Q);
  unsigned short* Kp    = (unsigned short*)(ws + OFF_K);
  unsigned short* Vt    = (unsigned short*)(ws + OFF_V);
  unsigned short* ctx   = hsb;

  // 1. convert hidden states to bf16
  int n4 = MTOT*HD/4;
  cvt_hs_kernel<<<(n4+255)/256, 256, 0, stream>>>(hs, hsb, n4);

  // 2. weights: transpose + convert to bf16 (n-major)
  dim3 bt(32, 8), gt(HD/32, HD/32);
  wt_cvt_kernel<<<gt, bt, 0, stream>>>(Wq, wqkvT);
  wt_cvt_kernel<<<gt, bt, 0, stream>>>(Wk, wqkvT + (size_t)HD*HD);
  wt_cvt_kernel<<<gt, bt, 0, stream>>>(Wv, wqkvT + (size_t)2*HD*HD);
  wt_cvt_kernel<<<gt, bt, 0, stream>>>(Wo, woT);

  // 3. zero Q only (its d-pads 72..79 must be 0 so K's garbage pads contribute 0;
  //    K s-pad rows are masked, V pad cols multiply p==0)
  hipMemsetAsync(ws + OFF_Q, 0, Q_BYTES, stream);

  // 4. QKV projection GEMM, scatter epilogue (Q pre-scaled by SCALE*log2e)
  gemm_kernel<1><<<(MPAD/128)*27, 256, 0, stream>>>(hsb, wqkvT, bq, bk, bv,
                                                    nullptr, Qp, Kp, Vt);

  // 5. fused attention -> ctx [MTOT][1152] bf16 (reuses hsb buffer)
  attn_kernel<<<1536, 256, 0, stream>>>(Qp, Kp, Vt, ctx);

  // 6. output projection GEMM -> fp32 out + bo
  gemm_kernel<0><<<(MPAD/128)*9, 256, 0, stream>>>(ctx, woT, bo, nullptr, nullptr,
                                                   out, nullptr, nullptr, nullptr);
}

// Round 3
// 428.101 us; speedup vs baseline: 1.1988x; 1.0056x over previous
//
#include <hip/hip_runtime.h>
#include <hip/hip_bf16.h>

// ---------------- problem constants ----------------
#define HD    1152
#define NHD   16        // heads
#define DH    72        // head dim
#define DHP   80        // padded head dim (5 x 16 for mfma K-chunks)
#define NB    16        // batch
#define SEQ   729
#define SP    736       // seq padded to x32 for K tiles
#define MTOT  (NB*SEQ)  // 11664
#define MPAD  11776     // 92 * 128
#define VROWS 96        // V d-rows padded to 3 x 32
// fold head_dim^-0.5 * log2(e) into Q so softmax runs in exp2 domain
#define QSCALE (0.117851130197757930f * 1.4426950408889634f)

typedef __attribute__((ext_vector_type(8))) short short8;
typedef __attribute__((ext_vector_type(4))) float f32x4;
typedef __attribute__((ext_vector_type(16))) float f32x16;
typedef __attribute__((ext_vector_type(4))) unsigned u32x4;

__device__ __forceinline__ unsigned short f2bf(float x){
  unsigned u = __float_as_uint(x);
  u += 0x7FFFu + ((u >> 16) & 1u);   // RNE
  return (unsigned short)(u >> 16);
}

__device__ __forceinline__ unsigned cvtpk_bf16(float lo, float hi){
  unsigned r;
  asm("v_cvt_pk_bf16_f32 %0, %1, %2" : "=v"(r) : "v"(lo), "v"(hi));
  return r;
}

#define GLD16(g, s) __builtin_amdgcn_global_load_lds( \
    (const __attribute__((address_space(1))) void*)(g), \
    (__attribute__((address_space(3))) void*)(s), 16, 0, 0)

// ---------------- workspace layout (bytes) ----------------
#define OFF_HSB   ((size_t)0)                    // MPAD*HD*2        = 27131904
#define OFF_WQKV  ((size_t)27131904)             // 3456*HD*2        =  7962624
#define OFF_WO    ((size_t)35094528)             // HD*HD*2          =  2654208
#define OFF_Q     ((size_t)37748736)             // 256*SEQ*DHP*2    = 29859840
#define OFF_K     ((size_t)67608576)             // 256*SP*DHP*2     = 30146560
#define OFF_V     ((size_t)97755136)             // 256*VROWS*SP*2   = 36175872
#define WS_END    ((size_t)133931008)
#define Q_BYTES   ((size_t)29859840)

// ---------------- fp32 -> bf16 convert (hidden states) ----------------
__global__ void cvt_hs_kernel(const float* __restrict__ in,
                              unsigned short* __restrict__ out, int n4){
  int i = blockIdx.x*256 + threadIdx.x;
  if (i >= n4) return;
  float4 v = ((const float4*)in)[i];
  ushort4 o;
  o.x = f2bf(v.x); o.y = f2bf(v.y); o.z = f2bf(v.z); o.w = f2bf(v.w);
  ((ushort4*)out)[i] = o;
}

// ---------------- weight transpose + convert: out[n][k] = bf16(W[k][n]) ----------------
__global__ void wt_cvt_kernel(const float* __restrict__ W,
                              unsigned short* __restrict__ outT){
  __shared__ float t[32][33];
  int k0 = blockIdx.x*32, n0 = blockIdx.y*32;
  int tx = threadIdx.x, ty = threadIdx.y;   // (32, 8)
  #pragma unroll
  for (int j=0;j<32;j+=8) t[ty+j][tx] = W[(size_t)(k0+ty+j)*HD + n0 + tx];
  __syncthreads();
  #pragma unroll
  for (int j=0;j<32;j+=8) outT[(size_t)(n0+ty+j)*HD + k0 + tx] = f2bf(t[tx][ty+j]);
}

// ---------------- bf16 GEMM: C[M][N] = A[M][K] * BT[N][K]^T ----------------
// 2-phase double-buffered LDS + XCD-chunked block swizzle.
// MODE 0: O-proj -> fp32 out + bias  (TILES_N = 9)
// MODE 1: QKV    -> scatter to padded Q/K/Vt + bias (TILES_N = 27)
template<int MODE>
__global__ __launch_bounds__(256) void gemm_kernel(
    const unsigned short* __restrict__ A, const unsigned short* __restrict__ BT,
    const float* __restrict__ bias_q, const float* __restrict__ bias_k,
    const float* __restrict__ bias_v,
    float* __restrict__ outF,
    unsigned short* __restrict__ Qp, unsigned short* __restrict__ Kp,
    unsigned short* __restrict__ Vt)
{
  constexpr int TILES_N = (MODE==1) ? 27 : 9;
  constexpr int NBLK = (MPAD/128)*TILES_N;
  constexpr int NT = HD/32;   // 36 K-steps

  // T1: bijective XCD-chunked swizzle (m204): XCD x owns a contiguous raster chunk
  int blk;
  {
    int orig = blockIdx.x;
    constexpr int q = NBLK >> 3, r = NBLK & 7;
    int xcd = orig & 7, idx = orig >> 3;
    blk = (xcd < r ? xcd*(q+1) : r*(q+1) + (xcd-r)*q) + idx;
  }
  const int tn = blk % TILES_N, tm = blk / TILES_N;
  const int tid = threadIdx.x, w = tid>>6, l = tid&63;
  const int lr = l&15, lg = l>>4;
  const int wm = w>>1, wn = w&1;

  __shared__ __align__(16) unsigned short As[2][128*32];
  __shared__ __align__(16) unsigned short Bs[2][128*32];

  const f32x4 z4 = {0.f,0.f,0.f,0.f};
  f32x4 acc[4][4];
  #pragma unroll
  for (int i=0;i<4;i++)
    #pragma unroll
    for (int j=0;j<4;j++) acc[i][j] = z4;

  // staging: wave w loads rows [w*32, w*32+32) of each 128x32 tile; lane -> row l>>2, col (l&3)*8
  const unsigned short* gA = A  + (size_t)(tm*128 + w*32 + (l>>2))*HD + (l&3)*8;
  const unsigned short* gB = BT + (size_t)(tn*128 + w*32 + (l>>2))*HD + (l&3)*8;

  // prologue: stage K-step 0 into buffer 0
  {
    unsigned short* lA = &As[0][w*1024];
    unsigned short* lB = &Bs[0][w*1024];
    GLD16(gA,          lA);
    GLD16(gA + 16*HD,  lA + 512);
    GLD16(gB,          lB);
    GLD16(gB + 16*HD,  lB + 512);
  }
  __syncthreads();   // drains vmcnt before first read

  #pragma unroll 2
  for (int kt = 0; kt < NT; kt++){
    const int cur = kt & 1;
    // ds-read current fragments
    short8 af[4], bfr[4];
    #pragma unroll
    for (int mi=0;mi<4;mi++) af[mi]  = *(const short8*)(&As[cur][0] + (wm*64 + mi*16 + lr)*32 + lg*8);
    #pragma unroll
    for (int ni=0;ni<4;ni++) bfr[ni] = *(const short8*)(&Bs[cur][0] + (wn*64 + ni*16 + lr)*32 + lg*8);
    // issue next-tile stage into the other buffer (latency hides under MFMA)
    if (kt + 1 < NT){
      const int kb = (kt+1)*32;
      unsigned short* lA = &As[cur^1][w*1024];
      unsigned short* lB = &Bs[cur^1][w*1024];
      GLD16(gA + kb,          lA);
      GLD16(gA + kb + 16*HD,  lA + 512);
      GLD16(gB + kb,          lB);
      GLD16(gB + kb + 16*HD,  lB + 512);
    }
    #pragma unroll
    for (int mi=0;mi<4;mi++)
      #pragma unroll
      for (int ni=0;ni<4;ni++)
        acc[mi][ni] = __builtin_amdgcn_mfma_f32_16x16x32_bf16(af[mi], bfr[ni], acc[mi][ni], 0, 0, 0);
    __syncthreads();   // all waves done reading cur; next-stage loads drained
  }

  if (MODE == 0){
    #pragma unroll
    for (int mi=0;mi<4;mi++){
      #pragma unroll
      for (int j=0;j<4;j++){
        int m = tm*128 + wm*64 + mi*16 + lg*4 + j;
        if (m < MTOT){
          #pragma unroll
          for (int ni=0;ni<4;ni++){
            int n = tn*128 + wn*64 + ni*16 + lr;
            outF[(size_t)m*HD + n] = acc[mi][ni][j] + bias_q[n];
          }
        }
      }
    }
  } else {
    #pragma unroll
    for (int mi=0;mi<4;mi++){
      #pragma unroll
      for (int j=0;j<4;j++){
        int m = tm*128 + wm*64 + mi*16 + lg*4 + j;
        if (m >= MTOT) continue;
        int b = m / SEQ;
        int s = m - b*SEQ;
        #pragma unroll
        for (int ni=0;ni<4;ni++){
          int n = tn*128 + wn*64 + ni*16 + lr;
          int mat = n / HD;
          int c = n - mat*HD;
          int h = c / DH;
          int d = c - h*DH;
          const float* bias = (mat==0) ? bias_q : (mat==1) ? bias_k : bias_v;
          float v = acc[mi][ni][j] + bias[c];
          int bh = b*NHD + h;
          if (mat == 0)      Qp[(size_t)bh*(SEQ*DHP) + (size_t)s*DHP + d] = f2bf(v*QSCALE);
          else if (mat == 1) Kp[(size_t)bh*(SP*DHP)  + (size_t)s*DHP + d] = f2bf(v);
          else               Vt[(size_t)bh*(VROWS*SP) + (size_t)d*SP + s] = f2bf(v);
        }
      }
    }
  }
}

// ---------------- PV sub-tile: pack P (in-register) -> bf16 frags, 6 MFMAs ----------------
__device__ __forceinline__ void pv_subtile(const f32x16 s, const unsigned short* __restrict__ vcol,
                                           int hi, f32x16 (&o)[3]){
  // s holds P[q][kcol_local] with kcol_local = (r&3)+8*(r>>2)+4*hi  (q = lane&31)
  unsigned A[4], B[4], xA[4], xB[4];
  #pragma unroll
  for (int g=0; g<4; g++){
    A[g]  = cvtpk_bf16(s[4*g+0], s[4*g+1]);
    B[g]  = cvtpk_bf16(s[4*g+2], s[4*g+3]);
    xA[g] = (unsigned)__shfl_xor((int)A[g], 32);
    xB[g] = (unsigned)__shfl_xor((int)B[g], 32);
  }
  #pragma unroll
  for (int ks=0; ks<2; ks++){
    unsigned w0 = hi ? xA[2*ks+1] : A[2*ks];
    unsigned w1 = hi ? xB[2*ks+1] : B[2*ks];
    unsigned w2 = hi ? A[2*ks+1]  : xA[2*ks];
    unsigned w3 = hi ? B[2*ks+1]  : xB[2*ks];
    u32x4 pw = {w0, w1, w2, w3};
    short8 pa = __builtin_bit_cast(short8, pw);
    #pragma unroll
    for (int dt=0; dt<3; dt++){
      short8 vf = *(const short8*)(vcol + (size_t)(dt*32)*SP + ks*16 + hi*8);
      o[dt] = __builtin_amdgcn_mfma_f32_32x32x16_bf16(pa, vf, o[dt], 0, 0, 0);
    }
  }
}

// ---------------- fused attention: 32 q-rows/wave, swapped QK^T, in-register softmax ----------------
__global__ __launch_bounds__(256) void attn_kernel(
    const unsigned short* __restrict__ Qp, const unsigned short* __restrict__ Kp,
    const unsigned short* __restrict__ Vt, unsigned short* __restrict__ ctx)
{
  const int blk = blockIdx.x;            // 0..1535
  const int xcd = blk & 7, ii = blk >> 3;
  const int bh  = xcd*32 + ii/6;         // 6 consecutive same-XCD blocks share one bh -> L2 reuse
  const int qt6 = ii % 6;
  const int tid = threadIdx.x, w = tid>>6, l = tid&63;
  const int lane = l & 31, hi = l >> 5;

  const int qbase = (qt6*4 + w)*32;
  if (qbase >= SEQ) return;              // wave-uniform; no barriers in this kernel

  const unsigned short* Qb = Qp + (size_t)bh*(SEQ*DHP);
  const unsigned short* Kb = Kp + (size_t)bh*(SP*DHP);
  const unsigned short* Vb = Vt + (size_t)bh*(VROWS*SP);

  int qr = qbase + lane; if (qr > SEQ-1) qr = SEQ-1;
  short8 qf[5];
  #pragma unroll
  for (int c=0;c<5;c++) qf[c] = *(const short8*)(Qb + (size_t)qr*DHP + c*16 + hi*8);

  f32x16 o[3];
  #pragma unroll
  for (int dt=0; dt<3; dt++)
    #pragma unroll
    for (int r=0;r<16;r++) o[dt][r] = 0.f;

  float m = -1e30f, lsum = 0.f;

  for (int kt=0; kt<12; kt++){
    const int kb = kt*64;
    f32x16 s0, s1;
    #pragma unroll
    for (int r=0;r<16;r++){ s0[r]=0.f; s1[r]=0.f; }

    const unsigned short* krow0 = Kb + (size_t)(kb + lane)*DHP + hi*8;
    #pragma unroll
    for (int c=0;c<5;c++){
      short8 kf = *(const short8*)(krow0 + c*16);
      s0 = __builtin_amdgcn_mfma_f32_32x32x16_bf16(kf, qf[c], s0, 0, 0, 0);
    }
    if (kt < 11){
      const unsigned short* krow1 = krow0 + 32*DHP;
      #pragma unroll
      for (int c=0;c<5;c++){
        short8 kf = *(const short8*)(krow1 + c*16);
        s1 = __builtin_amdgcn_mfma_f32_32x32x16_bf16(kf, qf[c], s1, 0, 0, 0);
      }
    } else {
      #pragma unroll
      for (int r=0;r<16;r++){
        const int base = 704 + (r&3) + 8*(r>>2);
        s0[r] = (base + 4*hi >= SEQ) ? -1e30f : s0[r];
        s1[r] = -1e30f;
      }
    }

    float tmax = -1e30f;
    #pragma unroll
    for (int r=0;r<16;r++) tmax = fmaxf(tmax, fmaxf(s0[r], s1[r]));
    tmax = fmaxf(tmax, __shfl_xor(tmax, 32));

    if (!__all(tmax <= m + 8.0f)){       // T13 defer-max (exp2 domain, THR=8)
      float mn = fmaxf(m, tmax);
      float sc = exp2f(m - mn);
      m = mn;
      lsum *= sc;
      #pragma unroll
      for (int dt=0; dt<3; dt++)
        #pragma unroll
        for (int r=0;r<16;r++) o[dt][r] *= sc;
    }

    float su = 0.f;
    #pragma unroll
    for (int r=0;r<16;r++){ float p = exp2f(s0[r]-m); s0[r]=p; su += p; }
    #pragma unroll
    for (int r=0;r<16;r++){ float p = exp2f(s1[r]-m); s1[r]=p; su += p; }
    su += __shfl_xor(su, 32);
    lsum += su;

    const unsigned short* vcol = Vb + (size_t)lane*SP + kb;
    pv_subtile(s0, vcol, hi, o);
    if (kt < 11) pv_subtile(s1, vcol + 32, hi, o);
  }

  float linv = 1.0f / lsum;
  const int b = bh >> 4, h = bh & 15;
  #pragma unroll
  for (int r=0;r<16;r++){
    const int qloc = (r&3) + 8*(r>>2) + 4*hi;
    float lv = __shfl(linv, qloc);
    int q = qbase + qloc;
    if (q < SEQ){
      unsigned short* crow = ctx + ((size_t)(b*SEQ + q))*HD + h*DH;
      #pragma unroll
      for (int dt=0; dt<3; dt++){
        int d = dt*32 + lane;
        if (d < DH) crow[d] = f2bf(o[dt][r] * lv);
      }
    }
  }
}

// ---------------- launcher ----------------
extern "C" void kernel_launch(void* const* d_in, const int* in_sizes, int n_in,
                              void* d_out, int out_size, void* d_ws, size_t ws_size,
                              hipStream_t stream) {
  const float* hs = (const float*)d_in[0];
  const float* Wq = (const float*)d_in[1]; const float* bq = (const float*)d_in[2];
  const float* Wk = (const float*)d_in[3]; const float* bk = (const float*)d_in[4];
  const float* Wv = (const float*)d_in[5]; const float* bv = (const float*)d_in[6];
  const float* Wo = (const float*)d_in[7]; const float* bo = (const float*)d_in[8];
  float* out = (float*)d_out;
  char* ws = (char*)d_ws;
  if (ws_size < WS_END) return;

  unsigned short* hsb   = (unsigned short*)(ws + OFF_HSB);  // later reused as ctx
  unsigned short* wqkvT = (unsigned short*)(ws + OFF_WQKV);
  unsigned short* woT   = (unsigned short*)(ws + OFF_WO);
  unsigned short* Qp    = (unsigned short*)(ws + OFF_Q);
  unsigned short* Kp    = (unsigned short*)(ws + OFF_K);
  unsigned short* Vt    = (unsigned short*)(ws + OFF_V);
  unsigned short* ctx   = hsb;

  // 1. convert hidden states to bf16
  int n4 = MTOT*HD/4;
  cvt_hs_kernel<<<(n4+255)/256, 256, 0, stream>>>(hs, hsb, n4);

  // 2. weights: transpose + convert to bf16 (n-major)
  dim3 bt(32, 8), gt(HD/32, HD/32);
  wt_cvt_kernel<<<gt, bt, 0, stream>>>(Wq, wqkvT);
  wt_cvt_kernel<<<gt, bt, 0, stream>>>(Wk, wqkvT + (size_t)HD*HD);
  wt_cvt_kernel<<<gt, bt, 0, stream>>>(Wv, wqkvT + (size_t)2*HD*HD);
  wt_cvt_kernel<<<gt, bt, 0, stream>>>(Wo, woT);

  // 3. zero Q only (its d-pads 72..79 must be 0 so K's garbage pads contribute 0;
  //    K s-pad rows are masked, V pad cols multiply p==0)
  hipMemsetAsync(ws + OFF_Q, 0, Q_BYTES, stream);

  // 4. QKV projection GEMM, scatter epilogue (Q pre-scaled by SCALE*log2e)
  gemm_kernel<1><<<(MPAD/128)*27, 256, 0, stream>>>(hsb, wqkvT, bq, bk, bv,
                                                    nullptr, Qp, Kp, Vt);

  // 5. fused attention -> ctx [MTOT][1152] bf16 (reuses hsb buffer)
  attn_kernel<<<1536, 256, 0, stream>>>(Qp, Kp, Vt, ctx);

  // 6. output projection GEMM -> fp32 out + bo
  gemm_kernel<0><<<(MPAD/128)*9, 256, 0, stream>>>(ctx, woT, bo, nullptr, nullptr,
                                                   out, nullptr, nullptr, nullptr);
}

// Round 4
// 418.633 us; speedup vs baseline: 1.2259x; 1.0226x over previous
//
#include <hip/hip_runtime.h>
#include <hip/hip_bf16.h>

// ---------------- problem constants ----------------
#define HD    1152
#define NHD   16        // heads
#define DH    72        // head dim
#define DHP   80        // padded head dim (5 x 16 for mfma K-chunks)
#define NB    16        // batch
#define SEQ   729
#define SP    736       // seq padded to x32 for K tiles
#define MTOT  (NB*SEQ)  // 11664
#define MPAD  11776     // 92 * 128
#define VROWS 96        // V d-rows padded to 3 x 32
// fold head_dim^-0.5 * log2(e) into Q so softmax runs in exp2 domain
#define QSCALE (0.117851130197757930f * 1.4426950408889634f)

typedef __attribute__((ext_vector_type(8))) short short8;
typedef __attribute__((ext_vector_type(4))) float f32x4;
typedef __attribute__((ext_vector_type(16))) float f32x16;
typedef __attribute__((ext_vector_type(4))) unsigned u32x4;

__device__ __forceinline__ unsigned short f2bf(float x){
  unsigned u = __float_as_uint(x);
  u += 0x7FFFu + ((u >> 16) & 1u);   // RNE
  return (unsigned short)(u >> 16);
}

__device__ __forceinline__ unsigned cvtpk_bf16(float lo, float hi){
  unsigned r;
  asm("v_cvt_pk_bf16_f32 %0, %1, %2" : "=v"(r) : "v"(lo), "v"(hi));
  return r;
}

#define GLD16(g, s) __builtin_amdgcn_global_load_lds( \
    (const __attribute__((address_space(1))) void*)(g), \
    (__attribute__((address_space(3))) void*)(s), 16, 0, 0)

// ---------------- workspace layout (bytes) ----------------
#define OFF_HSB   ((size_t)0)                    // MPAD*HD*2        = 27131904
#define OFF_WQKV  ((size_t)27131904)             // 3456*HD*2        =  7962624
#define OFF_WO    ((size_t)35094528)             // HD*HD*2          =  2654208
#define OFF_Q     ((size_t)37748736)             // 256*SEQ*DHP*2    = 29859840
#define OFF_K     ((size_t)67608576)             // 256*SP*DHP*2     = 30146560
#define OFF_V     ((size_t)97755136)             // 256*VROWS*SP*2   = 36175872
#define WS_END    ((size_t)133931008)
#define Q_BYTES   ((size_t)29859840)

// ---------------- fp32 -> bf16 convert (hidden states) ----------------
__global__ void cvt_hs_kernel(const float* __restrict__ in,
                              unsigned short* __restrict__ out, int n4){
  int i = blockIdx.x*256 + threadIdx.x;
  if (i >= n4) return;
  float4 v = ((const float4*)in)[i];
  ushort4 o;
  o.x = f2bf(v.x); o.y = f2bf(v.y); o.z = f2bf(v.z); o.w = f2bf(v.w);
  ((ushort4*)out)[i] = o;
}

// ---------------- weight transpose + convert: out[n][k] = bf16(W[k][n]) ----------------
__global__ void wt_cvt_kernel(const float* __restrict__ W,
                              unsigned short* __restrict__ outT){
  __shared__ float t[32][33];
  int k0 = blockIdx.x*32, n0 = blockIdx.y*32;
  int tx = threadIdx.x, ty = threadIdx.y;   // (32, 8)
  #pragma unroll
  for (int j=0;j<32;j+=8) t[ty+j][tx] = W[(size_t)(k0+ty+j)*HD + n0 + tx];
  __syncthreads();
  #pragma unroll
  for (int j=0;j<32;j+=8) outT[(size_t)(n0+ty+j)*HD + k0 + tx] = f2bf(t[tx][ty+j]);
}

// ---------------- bf16 GEMM: C[M][N] = A[M][K] * BT[N][K]^T ----------------
// counted-vmcnt 2-deep pipeline (raw s_barrier, no vmcnt(0) drain in loop)
// + XOR bank-swizzled LDS (pre-swizzled global source, lane-const read XOR)
// MODE 0: O-proj -> fp32 out + bias  (TILES_N = 9)
// MODE 1: QKV    -> scatter to padded Q/K/Vt + bias (TILES_N = 27)
template<int MODE>
__global__ __launch_bounds__(256) void gemm_kernel(
    const unsigned short* __restrict__ A, const unsigned short* __restrict__ BT,
    const float* __restrict__ bias_q, const float* __restrict__ bias_k,
    const float* __restrict__ bias_v,
    float* __restrict__ outF,
    unsigned short* __restrict__ Qp, unsigned short* __restrict__ Kp,
    unsigned short* __restrict__ Vt)
{
  constexpr int TILES_N = (MODE==1) ? 27 : 9;
  constexpr int NBLK = (MPAD/128)*TILES_N;
  constexpr int NT = HD/32;   // 36 K-steps

  // T1: bijective XCD-chunked swizzle (m204)
  int blk;
  {
    int orig = blockIdx.x;
    constexpr int q = NBLK >> 3, r = NBLK & 7;
    int xcd = orig & 7, idx = orig >> 3;
    blk = (xcd < r ? xcd*(q+1) : r*(q+1) + (xcd-r)*q) + idx;
  }
  const int tn = blk % TILES_N, tm = blk / TILES_N;
  const int tid = threadIdx.x, w = tid>>6, l = tid&63;
  const int lr = l&15, lg = l>>4;
  const int wm = w>>1, wn = w&1;
  const int srd = (lr ^ (lr>>2)) & 3;       // read-side swizzle (lane-const)

  __shared__ __align__(16) unsigned short As[2][128*32];
  __shared__ __align__(16) unsigned short Bs[2][128*32];

  const f32x4 z4 = {0.f,0.f,0.f,0.f};
  f32x4 acc[4][4];
  #pragma unroll
  for (int i=0;i<4;i++)
    #pragma unroll
    for (int j=0;j<4;j++) acc[i][j] = z4;

  // staging: wave w stages rows [w*32, w*32+32); lane -> row l>>2, stores LDS chunk l&3,
  // whose CONTENT is global chunk (l&3)^s(row), s(row) = (row ^ row>>2)&3 -> pre-swizzled source
  const unsigned short* gA = A  + (size_t)(tm*128 + w*32 + (l>>2))*HD + ((l ^ (l>>2) ^ (l>>4)) & 3)*8;
  const unsigned short* gB = BT + (size_t)(tn*128 + w*32 + (l>>2))*HD + ((l ^ (l>>2) ^ (l>>4)) & 3)*8;

#define STAGE_GEMM(kb, buf) do { \
    unsigned short* _lA = &As[buf][w*1024]; \
    unsigned short* _lB = &Bs[buf][w*1024]; \
    GLD16(gA + (kb),          _lA); \
    GLD16(gA + (kb) + 16*HD,  _lA + 512); \
    GLD16(gB + (kb),          _lB); \
    GLD16(gB + (kb) + 16*HD,  _lB + 512); \
  } while(0)

  // prologue: 2 tiles in flight (8 outstanding GLDs per thread)
  STAGE_GEMM(0, 0);
  STAGE_GEMM(32, 1);

  for (int kt = 0; kt < NT-1; kt++){
    const int cur = kt & 1;
    // my tile-kt loads landed (4 newer stay in flight); barrier => everyone's landed
    asm volatile("s_waitcnt vmcnt(4)" ::: "memory");
    __builtin_amdgcn_sched_barrier(0);
    __builtin_amdgcn_s_barrier();
    __builtin_amdgcn_sched_barrier(0);

    short8 af[4], bfr[4];
    #pragma unroll
    for (int mi=0;mi<4;mi++) af[mi]  = *(const short8*)(&As[cur][(wm*64 + mi*16 + lr)*32 + (lg ^ srd)*8]);
    #pragma unroll
    for (int ni=0;ni<4;ni++) bfr[ni] = *(const short8*)(&Bs[cur][(wn*64 + ni*16 + lr)*32 + (lg ^ srd)*8]);

    // my reads done; barrier => everyone's reads of buf[cur] done -> safe to overwrite
    asm volatile("s_waitcnt lgkmcnt(0)" ::: "memory");
    __builtin_amdgcn_sched_barrier(0);
    __builtin_amdgcn_s_barrier();
    __builtin_amdgcn_sched_barrier(0);

    if (kt + 2 < NT) STAGE_GEMM((kt+2)*32, cur);

    __builtin_amdgcn_s_setprio(1);
    #pragma unroll
    for (int mi=0;mi<4;mi++)
      #pragma unroll
      for (int ni=0;ni<4;ni++)
        acc[mi][ni] = __builtin_amdgcn_mfma_f32_16x16x32_bf16(af[mi], bfr[ni], acc[mi][ni], 0, 0, 0);
    __builtin_amdgcn_s_setprio(0);
  }
  // tail iteration (kt = NT-1, buf 1): only 4 outstanding -> full drain
  {
    constexpr int cur = (NT-1) & 1;
    asm volatile("s_waitcnt vmcnt(0)" ::: "memory");
    __builtin_amdgcn_sched_barrier(0);
    __builtin_amdgcn_s_barrier();
    __builtin_amdgcn_sched_barrier(0);
    short8 af[4], bfr[4];
    #pragma unroll
    for (int mi=0;mi<4;mi++) af[mi]  = *(const short8*)(&As[cur][(wm*64 + mi*16 + lr)*32 + (lg ^ srd)*8]);
    #pragma unroll
    for (int ni=0;ni<4;ni++) bfr[ni] = *(const short8*)(&Bs[cur][(wn*64 + ni*16 + lr)*32 + (lg ^ srd)*8]);
    #pragma unroll
    for (int mi=0;mi<4;mi++)
      #pragma unroll
      for (int ni=0;ni<4;ni++)
        acc[mi][ni] = __builtin_amdgcn_mfma_f32_16x16x32_bf16(af[mi], bfr[ni], acc[mi][ni], 0, 0, 0);
  }
#undef STAGE_GEMM

  if (MODE == 0){
    #pragma unroll
    for (int mi=0;mi<4;mi++){
      #pragma unroll
      for (int j=0;j<4;j++){
        int m = tm*128 + wm*64 + mi*16 + lg*4 + j;
        if (m < MTOT){
          #pragma unroll
          for (int ni=0;ni<4;ni++){
            int n = tn*128 + wn*64 + ni*16 + lr;
            outF[(size_t)m*HD + n] = acc[mi][ni][j] + bias_q[n];
          }
        }
      }
    }
  } else {
    #pragma unroll
    for (int mi=0;mi<4;mi++){
      #pragma unroll
      for (int j=0;j<4;j++){
        int m = tm*128 + wm*64 + mi*16 + lg*4 + j;
        if (m >= MTOT) continue;
        int b = m / SEQ;
        int s = m - b*SEQ;
        #pragma unroll
        for (int ni=0;ni<4;ni++){
          int n = tn*128 + wn*64 + ni*16 + lr;
          int mat = n / HD;
          int c = n - mat*HD;
          int h = c / DH;
          int d = c - h*DH;
          const float* bias = (mat==0) ? bias_q : (mat==1) ? bias_k : bias_v;
          float v = acc[mi][ni][j] + bias[c];
          int bh = b*NHD + h;
          if (mat == 0)      Qp[(size_t)bh*(SEQ*DHP) + (size_t)s*DHP + d] = f2bf(v*QSCALE);
          else if (mat == 1) Kp[(size_t)bh*(SP*DHP)  + (size_t)s*DHP + d] = f2bf(v);
          else               Vt[(size_t)bh*(VROWS*SP) + (size_t)d*SP + s] = f2bf(v);
        }
      }
    }
  }
}

// ---------------- PV sub-tile: pack P (in-register) -> bf16 frags, 6 MFMAs ----------------
__device__ __forceinline__ void pv_subtile(const f32x16 s, const unsigned short* __restrict__ vcol,
                                           int hi, f32x16 (&o)[3]){
  // s holds P[q][kcol_local] with kcol_local = (r&3)+8*(r>>2)+4*hi  (q = lane&31)
  unsigned A[4], B[4], xA[4], xB[4];
  #pragma unroll
  for (int g=0; g<4; g++){
    A[g]  = cvtpk_bf16(s[4*g+0], s[4*g+1]);
    B[g]  = cvtpk_bf16(s[4*g+2], s[4*g+3]);
    xA[g] = (unsigned)__shfl_xor((int)A[g], 32);
    xB[g] = (unsigned)__shfl_xor((int)B[g], 32);
  }
  __builtin_amdgcn_s_setprio(1);
  #pragma unroll
  for (int ks=0; ks<2; ks++){
    unsigned w0 = hi ? xA[2*ks+1] : A[2*ks];
    unsigned w1 = hi ? xB[2*ks+1] : B[2*ks];
    unsigned w2 = hi ? A[2*ks+1]  : xA[2*ks];
    unsigned w3 = hi ? B[2*ks+1]  : xB[2*ks];
    u32x4 pw = {w0, w1, w2, w3};
    short8 pa = __builtin_bit_cast(short8, pw);
    #pragma unroll
    for (int dt=0; dt<3; dt++){
      short8 vf = *(const short8*)(vcol + (size_t)(dt*32)*SP + ks*16 + hi*8);
      o[dt] = __builtin_amdgcn_mfma_f32_32x32x16_bf16(pa, vf, o[dt], 0, 0, 0);
    }
  }
  __builtin_amdgcn_s_setprio(0);
}

// ---------------- fused attention: 32 q-rows/wave, swapped QK^T, in-register softmax ----------------
__global__ __launch_bounds__(256) void attn_kernel(
    const unsigned short* __restrict__ Qp, const unsigned short* __restrict__ Kp,
    const unsigned short* __restrict__ Vt, unsigned short* __restrict__ ctx)
{
  const int blk = blockIdx.x;            // 0..1535
  const int xcd = blk & 7, ii = blk >> 3;
  const int bh  = xcd*32 + ii/6;         // 6 consecutive same-XCD blocks share one bh -> L2 reuse
  const int qt6 = ii % 6;
  const int tid = threadIdx.x, w = tid>>6, l = tid&63;
  const int lane = l & 31, hi = l >> 5;

  const int qbase = (qt6*4 + w)*32;
  if (qbase >= SEQ) return;              // wave-uniform; no barriers in this kernel

  const unsigned short* Qb = Qp + (size_t)bh*(SEQ*DHP);
  const unsigned short* Kb = Kp + (size_t)bh*(SP*DHP);
  const unsigned short* Vb = Vt + (size_t)bh*(VROWS*SP);

  int qr = qbase + lane; if (qr > SEQ-1) qr = SEQ-1;
  short8 qf[5];
  #pragma unroll
  for (int c=0;c<5;c++) qf[c] = *(const short8*)(Qb + (size_t)qr*DHP + c*16 + hi*8);

  f32x16 o[3];
  #pragma unroll
  for (int dt=0; dt<3; dt++)
    #pragma unroll
    for (int r=0;r<16;r++) o[dt][r] = 0.f;

  float m = -1e30f, lsum = 0.f;

  for (int kt=0; kt<12; kt++){
    const int kb = kt*64;
    f32x16 s0, s1;
    #pragma unroll
    for (int r=0;r<16;r++){ s0[r]=0.f; s1[r]=0.f; }

    const unsigned short* krow0 = Kb + (size_t)(kb + lane)*DHP + hi*8;
    __builtin_amdgcn_s_setprio(1);
    #pragma unroll
    for (int c=0;c<5;c++){
      short8 kf = *(const short8*)(krow0 + c*16);
      s0 = __builtin_amdgcn_mfma_f32_32x32x16_bf16(kf, qf[c], s0, 0, 0, 0);
    }
    __builtin_amdgcn_s_setprio(0);
    if (kt < 11){
      const unsigned short* krow1 = krow0 + 32*DHP;
      __builtin_amdgcn_s_setprio(1);
      #pragma unroll
      for (int c=0;c<5;c++){
        short8 kf = *(const short8*)(krow1 + c*16);
        s1 = __builtin_amdgcn_mfma_f32_32x32x16_bf16(kf, qf[c], s1, 0, 0, 0);
      }
      __builtin_amdgcn_s_setprio(0);
    } else {
      #pragma unroll
      for (int r=0;r<16;r++){
        const int base = 704 + (r&3) + 8*(r>>2);
        s0[r] = (base + 4*hi >= SEQ) ? -1e30f : s0[r];
        s1[r] = -1e30f;
      }
    }

    float tmax = -1e30f;
    #pragma unroll
    for (int r=0;r<16;r++) tmax = fmaxf(tmax, fmaxf(s0[r], s1[r]));
    tmax = fmaxf(tmax, __shfl_xor(tmax, 32));

    if (!__all(tmax <= m + 8.0f)){       // T13 defer-max (exp2 domain, THR=8)
      float mn = fmaxf(m, tmax);
      float sc = exp2f(m - mn);
      m = mn;
      lsum *= sc;
      #pragma unroll
      for (int dt=0; dt<3; dt++)
        #pragma unroll
        for (int r=0;r<16;r++) o[dt][r] *= sc;
    }

    float su = 0.f;
    #pragma unroll
    for (int r=0;r<16;r++){ float p = exp2f(s0[r]-m); s0[r]=p; su += p; }
    #pragma unroll
    for (int r=0;r<16;r++){ float p = exp2f(s1[r]-m); s1[r]=p; su += p; }
    su += __shfl_xor(su, 32);
    lsum += su;

    const unsigned short* vcol = Vb + (size_t)lane*SP + kb;
    pv_subtile(s0, vcol, hi, o);
    if (kt < 11) pv_subtile(s1, vcol + 32, hi, o);
  }

  float linv = 1.0f / lsum;
  const int b = bh >> 4, h = bh & 15;
  #pragma unroll
  for (int r=0;r<16;r++){
    const int qloc = (r&3) + 8*(r>>2) + 4*hi;
    float lv = __shfl(linv, qloc);
    int q = qbase + qloc;
    if (q < SEQ){
      unsigned short* crow = ctx + ((size_t)(b*SEQ + q))*HD + h*DH;
      #pragma unroll
      for (int dt=0; dt<3; dt++){
        int d = dt*32 + lane;
        if (d < DH) crow[d] = f2bf(o[dt][r] * lv);
      }
    }
  }
}

// ---------------- launcher ----------------
extern "C" void kernel_launch(void* const* d_in, const int* in_sizes, int n_in,
                              void* d_out, int out_size, void* d_ws, size_t ws_size,
                              hipStream_t stream) {
  const float* hs = (const float*)d_in[0];
  const float* Wq = (const float*)d_in[1]; const float* bq = (const float*)d_in[2];
  const float* Wk = (const float*)d_in[3]; const float* bk = (const float*)d_in[4];
  const float* Wv = (const float*)d_in[5]; const float* bv = (const float*)d_in[6];
  const float* Wo = (const float*)d_in[7]; const float* bo = (const float*)d_in[8];
  float* out = (float*)d_out;
  char* ws = (char*)d_ws;
  if (ws_size < WS_END) return;

  unsigned short* hsb   = (unsigned short*)(ws + OFF_HSB);  // later reused as ctx
  unsigned short* wqkvT = (unsigned short*)(ws + OFF_WQKV);
  unsigned short* woT   = (unsigned short*)(ws + OFF_WO);
  unsigned short* Qp    = (unsigned short*)(ws + OFF_Q);
  unsigned short* Kp    = (unsigned short*)(ws + OFF_K);
  unsigned short* Vt    = (unsigned short*)(ws + OFF_V);
  unsigned short* ctx   = hsb;

  // 1. convert hidden states to bf16
  int n4 = MTOT*HD/4;
  cvt_hs_kernel<<<(n4+255)/256, 256, 0, stream>>>(hs, hsb, n4);

  // 2. weights: transpose + convert to bf16 (n-major)
  dim3 bt(32, 8), gt(HD/32, HD/32);
  wt_cvt_kernel<<<gt, bt, 0, stream>>>(Wq, wqkvT);
  wt_cvt_kernel<<<gt, bt, 0, stream>>>(Wk, wqkvT + (size_t)HD*HD);
  wt_cvt_kernel<<<gt, bt, 0, stream>>>(Wv, wqkvT + (size_t)2*HD*HD);
  wt_cvt_kernel<<<gt, bt, 0, stream>>>(Wo, woT);

  // 3. zero Q only (its d-pads 72..79 must be 0 so K's garbage pads contribute 0;
  //    K s-pad rows are masked, V pad cols multiply p==0)
  hipMemsetAsync(ws + OFF_Q, 0, Q_BYTES, stream);

  // 4. QKV projection GEMM, scatter epilogue (Q pre-scaled by SCALE*log2e)
  gemm_kernel<1><<<(MPAD/128)*27, 256, 0, stream>>>(hsb, wqkvT, bq, bk, bv,
                                                    nullptr, Qp, Kp, Vt);

  // 5. fused attention -> ctx [MTOT][1152] bf16 (reuses hsb buffer)
  attn_kernel<<<1536, 256, 0, stream>>>(Qp, Kp, Vt, ctx);

  // 6. output projection GEMM -> fp32 out + bo
  gemm_kernel<0><<<(MPAD/128)*9, 256, 0, stream>>>(ctx, woT, bo, nullptr, nullptr,
                                                   out, nullptr, nullptr, nullptr);
}